// Round 14
// baseline (333.947 us; speedup 1.0000x reference)
//
#include <hip/hip_runtime.h>

typedef unsigned short u16;
typedef unsigned int   u32;
typedef __attribute__((ext_vector_type(8))) short short8;
typedef __attribute__((ext_vector_type(4))) float f32x4;

#define LOGM 4.852030263919617f

// workspace layout (float offsets)
constexpr int WS_PMAX = 0;         // 128 floats (per-combo stabilizer bound, by k_zs)
constexpr int WS_K1   = 2048;      // 128*128 floats (k1sum, atomic-accumulated)
constexpr int WS_KV   = 18432;     // 128*128*64 floats (kv [m][d], atomic-accumulated)
constexpr int WS_PHIK = 1067008;   // u16: 128 combos * 1056 * 128 (phi_k bf16, [s][m])

__device__ __forceinline__ float b2f(u16 u){ union { u32 i; float f; } x; x.i = ((u32)u) << 16; return x.f; }
__device__ __forceinline__ u16 f2b(float f){ union { float f; u32 i; } x; x.f = f; return (u16)((x.i + 0x7fffu + ((x.i >> 16) & 1u)) >> 16); }

// ========= k_zs: zero WS_K1+WS_KV (1040*256 float4 = 266240 exactly) + stab =========
__global__ __launch_bounds__(256) void k_zs(const float* __restrict__ proj,
                                            float* __restrict__ ws){
  __shared__ float red[2];
  const int bid = blockIdx.x, tid = threadIdx.x;
  const float4 z = {0.f,0.f,0.f,0.f};
  *(float4*)(ws + WS_K1 + ((size_t)bid*256 + tid)*4) = z;
  if(bid < 4 && tid < 128){
    const float4* pr = (const float4*)(proj + bid*8192 + tid*64);
    float pn = 0.f;
    #pragma unroll
    for(int i=0;i<16;i++){ float4 u = pr[i]; pn = fmaf(u.x,u.x,fmaf(u.y,u.y,fmaf(u.z,u.z,fmaf(u.w,u.w,pn)))); }
    #pragma unroll
    for(int o=1;o<64;o<<=1) pn = fmaxf(pn, __shfl_xor(pn, o));
    if((tid & 63) == 0) red[tid >> 6] = pn;
  }
  __syncthreads();
  if(bid < 4 && tid < 32){
    const float stab = 0.5f * fmaxf(red[0], red[1]);
    ws[WS_PMAX + bid*32 + tid] = stab;   // all combos with this c
  }
}

// ================= k_phi: logk MFMA -> phi_k -> ws; kv & k1 atomics =================
// r9: interleaved tile map + hoisted stab. r12: tile order rotated by (combo&3)*4
// to de-phase co-resident blocks (convoy break). ~122 us.
__global__ __launch_bounds__(256, 2) void k_phi(const float* __restrict__ key,
                                                const float* __restrict__ val,
                                                const float* __restrict__ proj,
                                                float* __restrict__ ws){
  __shared__ __align__(16) u16 phit[128*72];   // [m][key64] bf16, stride 72
  __shared__ __align__(16) u16 vt[64*72];      // [d][key64] bf16, stride 72, col-swizzled
  const int tid = threadIdx.x;
  const int wave = tid >> 6, l = tid & 63;
  const int g = l >> 4, r16 = l & 15;
  const int kq = blockIdx.x, combo = blockIdx.y;
  const int c = combo >> 5, b = (combo >> 3) & 3, h = combo & 7;
  const float* projc = proj + c*8192;
  const float stab = ws[WS_PMAX + combo];
  const int rot = (combo & 3) << 2;            // de-phase co-resident blocks

  short8 ph[8][2], pl[8][2];
  #pragma unroll
  for(int mt=0;mt<8;mt++){
    #pragma unroll
    for(int ks=0;ks<2;ks++){
      const float* pb = projc + (mt*16 + r16)*64 + ks*32 + g*8;
      float4 u0 = *(const float4*)pb;
      float4 u1 = *(const float4*)(pb + 4);
      float x[8] = {u0.x,u0.y,u0.z,u0.w,u1.x,u1.y,u1.z,u1.w};
      #pragma unroll
      for(int j=0;j<8;j++){
        u16 hb = f2b(x[j]);
        ph[mt][ks][j] = (short)hb;
        pl[mt][ks][j] = (short)f2b(x[j] - b2f(hb));
      }
    }
  }

  const f32x4 zero4 = {0.f,0.f,0.f,0.f};
  f32x4 kvacc[2][4];
  #pragma unroll
  for(int i=0;i<2;i++)
    #pragma unroll
    for(int j=0;j<4;j++) kvacc[i][j] = zero4;
  float k1p0 = 0.f, k1p1 = 0.f;
  u16* phikg = ((u16*)(ws + WS_PHIK)) + (size_t)combo*1056*128;

  for(int t0=0;t0<16;t0++){
    const int tt = (t0 + rot) & 15;
    const int s_tile = (kq + 4*tt)*64;      // interleaved tile map (rotated start)
    const bool dtile = (s_tile < 1056);
    const int sA = s_tile + wave*16 + r16;
    const float* krow = key + (size_t)(b*4096 + sA)*512 + h*64;
    float areg[16];
    #pragma unroll
    for(int ks=0;ks<2;ks++){
      float4 u0 = *(const float4*)(krow + ks*32 + g*8);
      float4 u1 = *(const float4*)(krow + ks*32 + g*8 + 4);
      areg[ks*8+0]=u0.x; areg[ks*8+1]=u0.y; areg[ks*8+2]=u0.z; areg[ks*8+3]=u0.w;
      areg[ks*8+4]=u1.x; areg[ks*8+5]=u1.y; areg[ks*8+6]=u1.z; areg[ks*8+7]=u1.w;
    }
    float4 vreg[4];
    #pragma unroll
    for(int i=0;i<4;i++){
      int flat = tid + 256*i;
      int sv = flat >> 4, d4 = (flat & 15)*4;
      vreg[i] = *(const float4*)(val + (size_t)(b*4096 + s_tile + sv)*512 + h*64 + d4);
    }
    float ksq = 0.f;
    #pragma unroll
    for(int e=0;e<16;e++) ksq = fmaf(areg[e], areg[e], ksq);
    ksq += __shfl_xor(ksq, 16);
    ksq += __shfl_xor(ksq, 32);
    ksq *= 0.5f;
    short8 ah[2], al[2];
    #pragma unroll
    for(int ks=0;ks<2;ks++){
      #pragma unroll
      for(int j=0;j<8;j++){
        float x = areg[ks*8+j];
        u16 hb = f2b(x);
        ah[ks][j] = (short)hb;
        al[ks][j] = (short)f2b(x - b2f(hb));
      }
    }
    f32x4 acc[8];
    #pragma unroll
    for(int mt=0;mt<8;mt++) acc[mt] = zero4;
    #pragma unroll
    for(int ks=0;ks<2;ks++){
      #pragma unroll
      for(int mt=0;mt<8;mt++){
        acc[mt] = __builtin_amdgcn_mfma_f32_16x16x32_bf16(ah[ks], ph[mt][ks], acc[mt], 0, 0, 0);
        acc[mt] = __builtin_amdgcn_mfma_f32_16x16x32_bf16(ah[ks], pl[mt][ks], acc[mt], 0, 0, 0);
        acc[mt] = __builtin_amdgcn_mfma_f32_16x16x32_bf16(al[ks], ph[mt][ks], acc[mt], 0, 0, 0);
      }
    }
    const float kc0 = __shfl(ksq, 4*g + 0);
    const float kc1 = __shfl(ksq, 4*g + 1);
    const float kc2 = __shfl(ksq, 4*g + 2);
    const float kc3 = __shfl(ksq, 4*g + 3);
    const int gs = s_tile + wave*16 + r16;
    #pragma unroll
    for(int mt=0;mt<8;mt++){
      ushort4 pw;
      pw.x = f2b(__expf(acc[mt][0] - kc0 - stab));
      pw.y = f2b(__expf(acc[mt][1] - kc1 - stab));
      pw.z = f2b(__expf(acc[mt][2] - kc2 - stab));
      pw.w = f2b(__expf(acc[mt][3] - kc3 - stab));
      *(ushort4*)(phit + (mt*16 + r16)*72 + wave*16 + 4*g) = pw;
      if(dtile && gs < 1056)
        *(ushort4*)(phikg + (size_t)gs*128 + mt*16 + 4*g) = pw;
    }
    #pragma unroll
    for(int i=0;i<4;i++){
      int flat = tid + 256*i;
      int sv = flat >> 4, d4 = (flat & 15)*4;
      float x[4] = {vreg[i].x, vreg[i].y, vreg[i].z, vreg[i].w};
      #pragma unroll
      for(int j=0;j<4;j++){
        int d = d4 + j;
        vt[d*72 + (sv ^ (8*((d>>2)&7)))] = f2b(x[j]);
      }
    }
    __syncthreads();
    #pragma unroll
    for(int ks=0;ks<2;ks++){
      short8 af0 = *(const short8*)(phit + ((2*wave+0)*16 + r16)*72 + ks*32 + g*8);
      short8 af1 = *(const short8*)(phit + ((2*wave+1)*16 + r16)*72 + ks*32 + g*8);
      short8 bf[4];
      #pragma unroll
      for(int dt=0;dt<4;dt++){
        int d = dt*16 + r16;
        int col = (ks*32 + g*8) ^ (8*((d>>2)&7));
        bf[dt] = *(const short8*)(vt + d*72 + col);
      }
      #pragma unroll
      for(int dt=0;dt<4;dt++){
        kvacc[0][dt] = __builtin_amdgcn_mfma_f32_16x16x32_bf16(af0, bf[dt], kvacc[0][dt], 0, 0, 0);
        kvacc[1][dt] = __builtin_amdgcn_mfma_f32_16x16x32_bf16(af1, bf[dt], kvacc[1][dt], 0, 0, 0);
      }
      #pragma unroll
      for(int j=0;j<8;j++){ k1p0 += b2f((u16)af0[j]); k1p1 += b2f((u16)af1[j]); }
    }
    __syncthreads();
  }
  k1p0 += __shfl_xor(k1p0, 16); k1p0 += __shfl_xor(k1p0, 32);
  k1p1 += __shfl_xor(k1p1, 16); k1p1 += __shfl_xor(k1p1, 32);
  if(l < 16){
    atomicAdd(ws + WS_K1 + combo*128 + (2*wave+0)*16 + l, k1p0);
    atomicAdd(ws + WS_K1 + combo*128 + (2*wave+1)*16 + l, k1p1);
  }
  #pragma unroll
  for(int mi=0;mi<2;mi++){
    #pragma unroll
    for(int dt=0;dt<4;dt++){
      #pragma unroll
      for(int rr=0;rr<4;rr++){
        int m = (2*wave+mi)*16 + 4*g + rr;
        int d = dt*16 + r16;
        atomicAdd(ws + WS_KV + (size_t)combo*8192 + m*64 + d, kvacc[mi][dt][rr]);
      }
    }
  }
}

// ================= k_qm: fused k_q + k_main =================
// r11: T14 hoist + write-swizzles. r13b: cj stride 136->104, LDS peak 53760 B
// -> 3 blocks/CU. cj swizzle mask is &3 (bits 3-4 only): write col = colfull^mask
// <= 95 < 104 and read base^mask+8 <= 96 <= 104 (the r13 &7 mask set bit 5 ->
// col up to 127 -> cross-row corruption, absmax 7.0).
__global__ __launch_bounds__(256, 3) void k_qm(const float* __restrict__ qry,
                                               const float* __restrict__ key,
                                               const float* __restrict__ val,
                                               const float* __restrict__ proj,
                                               float* __restrict__ ws,
                                               float* __restrict__ out){
  __shared__ __align__(16) u16 buf[26880];   // 53760 B
  // phase A layout
  u16* kvtA   = buf;            // [d][m] stride 136, col-swizzled
  u16* phiqsA = buf + 8704;     // [q][m] stride 136
  float* k1s  = (float*)(buf + 17408);   // 128 floats
  // phase B layout (overlays; all phase-A reads complete before reuse)
  u16* khs  = buf;              // [96][72]
  u16* kls  = buf + 6912;
  u16* phik = buf + 13824;      // [96][136] -> ends 26880
  u16* cjh  = buf;              // [64][104], col-swizzled (&3)
  u16* cjl  = buf + 6656;
  u16* vt   = buf + 13312;      // [64][104], col-swizzled (&3)
  u16* vtl  = buf + 19968;      // ends 26624

  const int tid = threadIdx.x;
  const int wave = tid >> 6, l = tid & 63;
  const int g = l >> 4, r16 = l & 15;
  const int qt = blockIdx.x, combo = blockIdx.y;
  const int c = combo >> 5, b = (combo >> 3) & 3, h = combo & 7;
  const int s_base = qt*64 - 16;
  const float* projc = proj + c*8192;
  const float stab = ws[WS_PMAX + combo];
  const f32x4 zero4 = {0.f,0.f,0.f,0.f};

  // ---- prefetch ALL phase-B global inputs (consumed after A2) — T14
  const u16* phikg = ((const u16*)(ws + WS_PHIK)) + (size_t)combo*1056*128;
  float4 kreg[6], vreg[6];
  ushort4 preg[12];
  #pragma unroll
  for(int i=0;i<6;i++){
    int flat = tid + 256*i;
    int j = flat >> 4, e4 = (flat & 15)*4;
    int s = s_base + j;
    float4 u = {0.f,0.f,0.f,0.f};
    float4 w4 = {0.f,0.f,0.f,0.f};
    if(s >= 0){
      u  = *(const float4*)(key + (((size_t)b*4096 + s)*8 + h)*64 + e4);
      w4 = *(const float4*)(val + (((size_t)b*4096 + s)*8 + h)*64 + e4);
    }
    kreg[i] = u; vreg[i] = w4;
  }
  #pragma unroll
  for(int i=0;i<12;i++){
    int flat = tid + 256*i;
    int j = flat >> 5, c4 = (flat & 31)*4;
    int s = s_base + j;
    ushort4 p = {0,0,0,0};
    if(s >= 0) p = *(const ushort4*)(phikg + (size_t)s*128 + c4);
    preg[i] = p;
  }

  // ---- A0: k1s + kv -> LDS (transposed bf16, col-swizzled)
  if(tid < 128) k1s[tid] = ws[WS_K1 + combo*128 + tid];
  const float* kvg = ws + WS_KV + (size_t)combo*8192;
  #pragma unroll
  for(int i=0;i<8;i++){
    int flat = tid + 256*i;
    int m = flat >> 4, d4 = (flat & 15)*4;
    int col = m ^ (8*((flat & 15) & 7));   // swz by (d>>2)&7 = (flat&15)&7
    float4 u = *(const float4*)(kvg + m*64 + d4);
    kvtA[(d4+0)*136 + col] = f2b(u.x);
    kvtA[(d4+1)*136 + col] = f2b(u.y);
    kvtA[(d4+2)*136 + col] = f2b(u.z);
    kvtA[(d4+3)*136 + col] = f2b(u.w);
  }
  // q fragments (hi/lo) — used by BOTH logq (phase A) and scores (phase B)
  const int qrow = qt*64 + wave*16 + r16;
  const float* qr = qry + (size_t)(b*4096 + (c*1024 + qrow))*512 + h*64;
  float areg[16];
  #pragma unroll
  for(int ks=0;ks<2;ks++){
    float4 u0 = *(const float4*)(qr + ks*32 + g*8);
    float4 u1 = *(const float4*)(qr + ks*32 + g*8 + 4);
    areg[ks*8+0]=u0.x; areg[ks*8+1]=u0.y; areg[ks*8+2]=u0.z; areg[ks*8+3]=u0.w;
    areg[ks*8+4]=u1.x; areg[ks*8+5]=u1.y; areg[ks*8+6]=u1.z; areg[ks*8+7]=u1.w;
  }
  float qsq = 0.f;
  #pragma unroll
  for(int e=0;e<16;e++) qsq = fmaf(areg[e], areg[e], qsq);
  qsq += __shfl_xor(qsq, 16);
  qsq += __shfl_xor(qsq, 32);
  qsq *= 0.5f;
  short8 ah[2], al[2];
  #pragma unroll
  for(int ks=0;ks<2;ks++){
    #pragma unroll
    for(int j=0;j<8;j++){
      float x = areg[ks*8+j];
      u16 hb = f2b(x);
      ah[ks][j] = (short)hb;
      al[ks][j] = (short)f2b(x - b2f(hb));
    }
  }
  __syncthreads();   // kvtA, k1s ready

  // ---- A1: logq MFMA
  f32x4 acc[8];
  #pragma unroll
  for(int mt=0;mt<8;mt++) acc[mt] = zero4;
  #pragma unroll
  for(int ks=0;ks<2;ks++){
    #pragma unroll
    for(int mt=0;mt<8;mt++){
      const float* pb = projc + (mt*16 + r16)*64 + ks*32 + g*8;
      float4 u0 = *(const float4*)pb;
      float4 u1 = *(const float4*)(pb + 4);
      float x[8] = {u0.x,u0.y,u0.z,u0.w,u1.x,u1.y,u1.z,u1.w};
      short8 pph, ppl;
      #pragma unroll
      for(int j=0;j<8;j++){
        u16 hb = f2b(x[j]);
        pph[j] = (short)hb;
        ppl[j] = (short)f2b(x[j] - b2f(hb));
      }
      acc[mt] = __builtin_amdgcn_mfma_f32_16x16x32_bf16(ah[ks], pph, acc[mt], 0, 0, 0);
      acc[mt] = __builtin_amdgcn_mfma_f32_16x16x32_bf16(ah[ks], ppl, acc[mt], 0, 0, 0);
      acc[mt] = __builtin_amdgcn_mfma_f32_16x16x32_bf16(al[ks], pph, acc[mt], 0, 0, 0);
    }
  }
  float qsr[4];
  #pragma unroll
  for(int r=0;r<4;r++) qsr[r] = __shfl(qsq, 4*g + r);
  float amax[4];
  #pragma unroll
  for(int r=0;r<4;r++){
    float m = -3e38f;
    #pragma unroll
    for(int mt=0;mt<8;mt++) m = fmaxf(m, acc[mt][r]);
    m = fmaxf(m, __shfl_xor(m, 1));
    m = fmaxf(m, __shfl_xor(m, 2));
    m = fmaxf(m, __shfl_xor(m, 4));
    m = fmaxf(m, __shfl_xor(m, 8));
    amax[r] = m;
  }
  float lrp[4] = {0.f,0.f,0.f,0.f};
  #pragma unroll
  for(int mt=0;mt<8;mt++){
    const float k1v = k1s[mt*16 + r16];
    #pragma unroll
    for(int r=0;r<4;r++){
      float phv = __expf(acc[mt][r] - amax[r]);
      phiqsA[(wave*16 + 4*g + r)*136 + mt*16 + r16] = f2b(phv);
      lrp[r] = fmaf(phv, k1v, lrp[r]);
    }
  }
  #pragma unroll
  for(int r=0;r<4;r++){
    lrp[r] += __shfl_xor(lrp[r], 1);
    lrp[r] += __shfl_xor(lrp[r], 2);
    lrp[r] += __shfl_xor(lrp[r], 4);
    lrp[r] += __shfl_xor(lrp[r], 8);
  }
  float plsr[4], lr1r[4];
  #pragma unroll
  for(int r=0;r<4;r++){
    plsr[r] = amax[r] - qsr[r] + stab - LOGM;
    lr1r[r] = lrp[r];
  }
  __syncthreads();   // phiqsA complete

  // ---- A2: phi_q A-fragments + lr_v MFMA (f32, kept in regs)
  short8 pa[4];
  #pragma unroll
  for(int ks=0;ks<4;ks++)
    pa[ks] = *(const short8*)(phiqsA + (wave*16 + r16)*136 + ks*32 + g*8);
  f32x4 lacc[4];
  #pragma unroll
  for(int dt=0;dt<4;dt++) lacc[dt] = zero4;
  #pragma unroll
  for(int ks=0;ks<4;ks++){
    #pragma unroll
    for(int dt=0;dt<4;dt++){
      int drow = dt*16 + r16;
      int colb = (ks*32 + g*8) ^ (8*((drow>>2)&7));
      short8 bfr = *(const short8*)(kvtA + drow*136 + colb);
      lacc[dt] = __builtin_amdgcn_mfma_f32_16x16x32_bf16(pa[ks], bfr, lacc[dt], 0, 0, 0);
    }
  }
  __syncthreads();   // all phase-A LDS reads done; buf may be overwritten

  // ---- B0: write prefetched k window (hi/lo) + phi_k window to LDS
  #pragma unroll
  for(int i=0;i<6;i++){
    int flat = tid + 256*i;
    int j = flat >> 4, e4 = (flat & 15)*4;
    float4 u = kreg[i];
    ushort4 hh, ll;
    hh.x = f2b(u.x); ll.x = f2b(u.x - b2f(hh.x));
    hh.y = f2b(u.y); ll.y = f2b(u.y - b2f(hh.y));
    hh.z = f2b(u.z); ll.z = f2b(u.z - b2f(hh.z));
    hh.w = f2b(u.w); ll.w = f2b(u.w - b2f(hh.w));
    *(ushort4*)(khs + j*72 + e4) = hh;
    *(ushort4*)(kls + j*72 + e4) = ll;
  }
  #pragma unroll
  for(int i=0;i<12;i++){
    int flat = tid + 256*i;
    int j = flat >> 5, c4 = (flat & 31)*4;
    *(ushort4*)(phik + j*136 + c4) = preg[i];
  }
  __syncthreads();

  // ---- B1: S (scores) and D (dots_p) over the full 16x96 stripe
  f32x4 sacc[6], dacc[6];
  #pragma unroll
  for(int j=0;j<6;j++){ sacc[j] = zero4; dacc[j] = zero4; }
  #pragma unroll
  for(int j=0;j<6;j++){
    #pragma unroll
    for(int ks=0;ks<2;ks++){
      short8 kbh = *(const short8*)(khs + (j*16 + r16)*72 + ks*32 + g*8);
      short8 kbl = *(const short8*)(kls + (j*16 + r16)*72 + ks*32 + g*8);
      sacc[j] = __builtin_amdgcn_mfma_f32_16x16x32_bf16(ah[ks], kbh, sacc[j], 0, 0, 0);
      sacc[j] = __builtin_amdgcn_mfma_f32_16x16x32_bf16(al[ks], kbh, sacc[j], 0, 0, 0);
      sacc[j] = __builtin_amdgcn_mfma_f32_16x16x32_bf16(ah[ks], kbl, sacc[j], 0, 0, 0);
    }
    #pragma unroll
    for(int ks=0;ks<4;ks++){
      short8 pb = *(const short8*)(phik + (j*16 + r16)*136 + ks*32 + g*8);
      dacc[j] = __builtin_amdgcn_mfma_f32_16x16x32_bf16(pa[ks], pb, dacc[j], 0, 0, 0);
    }
  }
  __syncthreads();   // all B1 LDS reads done; region reused below

  // ---- B2: v -> LDS (transposed, hi/lo, col-swizzled); softmax; cj -> LDS (swizzled)
  #pragma unroll
  for(int i=0;i<6;i++){
    int flat = tid + 256*i;
    int j = flat >> 4, e4 = (flat & 15)*4;
    int e = flat & 15;
    int col = j ^ (8*(e & 3));             // swz by (row>>2)&3 = e&3
    float4 u = vreg[i];
    u16 h0 = f2b(u.x), h1 = f2b(u.y), h2 = f2b(u.z), h3 = f2b(u.w);
    vt[(e4+0)*104 + col] = h0; vtl[(e4+0)*104 + col] = f2b(u.x - b2f(h0));
    vt[(e4+1)*104 + col] = h1; vtl[(e4+1)*104 + col] = f2b(u.y - b2f(h1));
    vt[(e4+2)*104 + col] = h2; vtl[(e4+2)*104 + col] = f2b(u.z - b2f(h2));
    vt[(e4+3)*104 + col] = h3; vtl[(e4+3)*104 + col] = f2b(u.w - b2f(h3));
  }
  const int rowb = wave*16 + 4*g;
  float m1r[4] = {-1e30f,-1e30f,-1e30f,-1e30f};
  #pragma unroll
  for(int j=0;j<6;j++){
    #pragma unroll
    for(int r=0;r<4;r++){
      int rel = 16*j + r16 - 16 - (rowb + r);
      bool ok = (rel >= -16) && (rel < 16) && (s_base + 16*j + r16 >= 0);
      if(ok) m1r[r] = fmaxf(m1r[r], sacc[j][r]);
    }
  }
  #pragma unroll
  for(int r=0;r<4;r++){
    m1r[r] = fmaxf(m1r[r], __shfl_xor(m1r[r], 1));
    m1r[r] = fmaxf(m1r[r], __shfl_xor(m1r[r], 2));
    m1r[r] = fmaxf(m1r[r], __shfl_xor(m1r[r], 4));
    m1r[r] = fmaxf(m1r[r], __shfl_xor(m1r[r], 8));
  }
  float ser[4] = {0.f,0.f,0.f,0.f}, wpr[4] = {0.f,0.f,0.f,0.f};
  #pragma unroll
  for(int j=0;j<6;j++){
    #pragma unroll
    for(int r=0;r<4;r++){
      int rel = 16*j + r16 - 16 - (rowb + r);
      bool ok = (rel >= -16) && (rel < 16) && (s_base + 16*j + r16 >= 0);
      if(ok){
        ser[r] += __expf(sacc[j][r] - m1r[r]);
        wpr[r] += dacc[j][r];
      }
    }
  }
  #pragma unroll
  for(int r=0;r<4;r++){
    ser[r] += __shfl_xor(ser[r], 1); ser[r] += __shfl_xor(ser[r], 2);
    ser[r] += __shfl_xor(ser[r], 4); ser[r] += __shfl_xor(ser[r], 8);
    wpr[r] += __shfl_xor(wpr[r], 1); wpr[r] += __shfl_xor(wpr[r], 2);
    wpr[r] += __shfl_xor(wpr[r], 4); wpr[r] += __shfl_xor(wpr[r], 8);
  }
  float lnr[4], scr[4];
  #pragma unroll
  for(int r=0;r<4;r++){
    float qk_lse = m1r[r] + __logf(ser[r]);
    float lrem = fmaxf(lr1r[r] - wpr[r], 1e-37f);
    float bb = __logf(lrem) + plsr[r];
    float ln = fmaxf(qk_lse, bb) + log1pf(__expf(-fabsf(qk_lse - bb)));
    lnr[r] = ln;
    scr[r] = __expf(plsr[r] - ln);
  }
  #pragma unroll
  for(int j=0;j<6;j++){
    #pragma unroll
    for(int r=0;r<4;r++){
      int rel = 16*j + r16 - 16 - (rowb + r);
      bool ok = (rel >= -16) && (rel < 16) && (s_base + 16*j + r16 >= 0);
      float cj = ok ? (__expf(sacc[j][r] - lnr[r]) - scr[r]*dacc[j][r]) : 0.f;
      u16 hb = f2b(cj);
      int row = rowb + r;
      int col = (16*j + r16) ^ (8*((row>>2)&3));   // mask bits 3-4 only: col <= 95 < 104
      cjh[row*104 + col] = hb;
      cjl[row*104 + col] = f2b(cj - b2f(hb));
    }
  }
  __syncthreads();

  // ---- B3: out = cj . v_win (hi/lo split) + scale*lr_v (lacc, f32)
  f32x4 oacc[4];
  #pragma unroll
  for(int dt=0;dt<4;dt++) oacc[dt] = zero4;
  const int qrowB = wave*16 + r16;
  const int cw = (qrowB >> 2) & 3;        // matches write mask (&3)
  #pragma unroll
  for(int ks=0;ks<3;ks++){
    int ccol = (ks*32 + g*8) ^ (8*cw);    // base^mask <= 88, +8 = 96 <= 104
    short8 ch = *(const short8*)(cjh + qrowB*104 + ccol);
    short8 cl = *(const short8*)(cjl + qrowB*104 + ccol);
    #pragma unroll
    for(int dt=0;dt<4;dt++){
      int vrow = dt*16 + r16;
      int vcol = (ks*32 + g*8) ^ (8*((vrow>>2)&3));
      short8 vbh = *(const short8*)(vt  + vrow*104 + vcol);
      short8 vbl = *(const short8*)(vtl + vrow*104 + vcol);
      oacc[dt] = __builtin_amdgcn_mfma_f32_16x16x32_bf16(ch, vbh, oacc[dt], 0, 0, 0);
      oacc[dt] = __builtin_amdgcn_mfma_f32_16x16x32_bf16(cl, vbh, oacc[dt], 0, 0, 0);
      oacc[dt] = __builtin_amdgcn_mfma_f32_16x16x32_bf16(ch, vbl, oacc[dt], 0, 0, 0);
    }
  }
  #pragma unroll
  for(int r=0;r<4;r++){
    int row = rowb + r;                      // query within 64
    float* ob = out + ((((size_t)b*8 + h)*4096) + (size_t)c*1024 + qt*64 + row)*64;
    #pragma unroll
    for(int dt=0;dt<4;dt++)
      ob[dt*16 + r16] = oacc[dt][r] + scr[r]*lacc[dt][r];
  }
}

extern "C" void kernel_launch(void* const* d_in, const int* in_sizes, int n_in,
                              void* d_out, int out_size, void* d_ws, size_t ws_size,
                              hipStream_t stream){
  (void)in_sizes; (void)n_in; (void)out_size; (void)ws_size;
  const float* q = (const float*)d_in[0];
  const float* k = (const float*)d_in[1];
  const float* v = (const float*)d_in[2];
  const float* p = (const float*)d_in[3];
  float* out = (float*)d_out;
  float* ws = (float*)d_ws;
  k_zs  <<<dim3(1040),   256, 0, stream>>>(p, ws);
  k_phi <<<dim3(4,128),  256, 0, stream>>>(k, v, p, ws);
  k_qm  <<<dim3(16,128), 256, 0, stream>>>(q, k, v, p, ws, out);
}

// Round 15
// 307.099 us; speedup vs baseline: 1.0874x; 1.0874x over previous
//
#include <hip/hip_runtime.h>

typedef unsigned short u16;
typedef unsigned int   u32;
typedef __attribute__((ext_vector_type(8))) short short8;
typedef __attribute__((ext_vector_type(4))) float f32x4;

#define LOGM 4.852030263919617f

// workspace layout (float offsets)
constexpr int WS_PMAX = 0;         // 128 floats (per-combo stabilizer bound, by k_zs)
constexpr int WS_K1   = 2048;      // 128*128 floats (k1sum, atomic-accumulated)
constexpr int WS_KV   = 18432;     // 128*128*64 floats (kv [m][d], atomic-accumulated)
constexpr int WS_PHIK = 1067008;   // u16: 128 combos * 1056 * 128 (phi_k bf16, [s][m])

__device__ __forceinline__ float b2f(u16 u){ union { u32 i; float f; } x; x.i = ((u32)u) << 16; return x.f; }
__device__ __forceinline__ u16 f2b(float f){ union { float f; u32 i; } x; x.f = f; return (u16)((x.i + 0x7fffu + ((x.i >> 16) & 1u)) >> 16); }

// ========= k_zs: zero WS_K1+WS_KV (1040*256 float4 = 266240 exactly) + stab =========
__global__ __launch_bounds__(256) void k_zs(const float* __restrict__ proj,
                                            float* __restrict__ ws){
  __shared__ float red[2];
  const int bid = blockIdx.x, tid = threadIdx.x;
  const float4 z = {0.f,0.f,0.f,0.f};
  *(float4*)(ws + WS_K1 + ((size_t)bid*256 + tid)*4) = z;
  if(bid < 4 && tid < 128){
    const float4* pr = (const float4*)(proj + bid*8192 + tid*64);
    float pn = 0.f;
    #pragma unroll
    for(int i=0;i<16;i++){ float4 u = pr[i]; pn = fmaf(u.x,u.x,fmaf(u.y,u.y,fmaf(u.z,u.z,fmaf(u.w,u.w,pn)))); }
    #pragma unroll
    for(int o=1;o<64;o<<=1) pn = fmaxf(pn, __shfl_xor(pn, o));
    if((tid & 63) == 0) red[tid >> 6] = pn;
  }
  __syncthreads();
  if(bid < 4 && tid < 32){
    const float stab = 0.5f * fmaxf(red[0], red[1]);
    ws[WS_PMAX + bid*32 + tid] = stab;   // all combos with this c
  }
}

// ================= k_phi: logk MFMA -> phi_k -> ws; kv & k1 atomics =================
// r9: interleaved tile map + hoisted stab. r12: tile order rotated by (combo&3)*4
// to de-phase co-resident blocks (convoy break). ~122 us.
__global__ __launch_bounds__(256, 2) void k_phi(const float* __restrict__ key,
                                                const float* __restrict__ val,
                                                const float* __restrict__ proj,
                                                float* __restrict__ ws){
  __shared__ __align__(16) u16 phit[128*72];   // [m][key64] bf16, stride 72
  __shared__ __align__(16) u16 vt[64*72];      // [d][key64] bf16, stride 72, col-swizzled
  const int tid = threadIdx.x;
  const int wave = tid >> 6, l = tid & 63;
  const int g = l >> 4, r16 = l & 15;
  const int kq = blockIdx.x, combo = blockIdx.y;
  const int c = combo >> 5, b = (combo >> 3) & 3, h = combo & 7;
  const float* projc = proj + c*8192;
  const float stab = ws[WS_PMAX + combo];
  const int rot = (combo & 3) << 2;            // de-phase co-resident blocks

  short8 ph[8][2], pl[8][2];
  #pragma unroll
  for(int mt=0;mt<8;mt++){
    #pragma unroll
    for(int ks=0;ks<2;ks++){
      const float* pb = projc + (mt*16 + r16)*64 + ks*32 + g*8;
      float4 u0 = *(const float4*)pb;
      float4 u1 = *(const float4*)(pb + 4);
      float x[8] = {u0.x,u0.y,u0.z,u0.w,u1.x,u1.y,u1.z,u1.w};
      #pragma unroll
      for(int j=0;j<8;j++){
        u16 hb = f2b(x[j]);
        ph[mt][ks][j] = (short)hb;
        pl[mt][ks][j] = (short)f2b(x[j] - b2f(hb));
      }
    }
  }

  const f32x4 zero4 = {0.f,0.f,0.f,0.f};
  f32x4 kvacc[2][4];
  #pragma unroll
  for(int i=0;i<2;i++)
    #pragma unroll
    for(int j=0;j<4;j++) kvacc[i][j] = zero4;
  float k1p0 = 0.f, k1p1 = 0.f;
  u16* phikg = ((u16*)(ws + WS_PHIK)) + (size_t)combo*1056*128;

  for(int t0=0;t0<16;t0++){
    const int tt = (t0 + rot) & 15;
    const int s_tile = (kq + 4*tt)*64;      // interleaved tile map (rotated start)
    const bool dtile = (s_tile < 1056);
    const int sA = s_tile + wave*16 + r16;
    const float* krow = key + (size_t)(b*4096 + sA)*512 + h*64;
    float areg[16];
    #pragma unroll
    for(int ks=0;ks<2;ks++){
      float4 u0 = *(const float4*)(krow + ks*32 + g*8);
      float4 u1 = *(const float4*)(krow + ks*32 + g*8 + 4);
      areg[ks*8+0]=u0.x; areg[ks*8+1]=u0.y; areg[ks*8+2]=u0.z; areg[ks*8+3]=u0.w;
      areg[ks*8+4]=u1.x; areg[ks*8+5]=u1.y; areg[ks*8+6]=u1.z; areg[ks*8+7]=u1.w;
    }
    float4 vreg[4];
    #pragma unroll
    for(int i=0;i<4;i++){
      int flat = tid + 256*i;
      int sv = flat >> 4, d4 = (flat & 15)*4;
      vreg[i] = *(const float4*)(val + (size_t)(b*4096 + s_tile + sv)*512 + h*64 + d4);
    }
    float ksq = 0.f;
    #pragma unroll
    for(int e=0;e<16;e++) ksq = fmaf(areg[e], areg[e], ksq);
    ksq += __shfl_xor(ksq, 16);
    ksq += __shfl_xor(ksq, 32);
    ksq *= 0.5f;
    short8 ah[2], al[2];
    #pragma unroll
    for(int ks=0;ks<2;ks++){
      #pragma unroll
      for(int j=0;j<8;j++){
        float x = areg[ks*8+j];
        u16 hb = f2b(x);
        ah[ks][j] = (short)hb;
        al[ks][j] = (short)f2b(x - b2f(hb));
      }
    }
    f32x4 acc[8];
    #pragma unroll
    for(int mt=0;mt<8;mt++) acc[mt] = zero4;
    #pragma unroll
    for(int ks=0;ks<2;ks++){
      #pragma unroll
      for(int mt=0;mt<8;mt++){
        acc[mt] = __builtin_amdgcn_mfma_f32_16x16x32_bf16(ah[ks], ph[mt][ks], acc[mt], 0, 0, 0);
        acc[mt] = __builtin_amdgcn_mfma_f32_16x16x32_bf16(ah[ks], pl[mt][ks], acc[mt], 0, 0, 0);
        acc[mt] = __builtin_amdgcn_mfma_f32_16x16x32_bf16(al[ks], ph[mt][ks], acc[mt], 0, 0, 0);
      }
    }
    const float kc0 = __shfl(ksq, 4*g + 0);
    const float kc1 = __shfl(ksq, 4*g + 1);
    const float kc2 = __shfl(ksq, 4*g + 2);
    const float kc3 = __shfl(ksq, 4*g + 3);
    const int gs = s_tile + wave*16 + r16;
    #pragma unroll
    for(int mt=0;mt<8;mt++){
      ushort4 pw;
      pw.x = f2b(__expf(acc[mt][0] - kc0 - stab));
      pw.y = f2b(__expf(acc[mt][1] - kc1 - stab));
      pw.z = f2b(__expf(acc[mt][2] - kc2 - stab));
      pw.w = f2b(__expf(acc[mt][3] - kc3 - stab));
      *(ushort4*)(phit + (mt*16 + r16)*72 + wave*16 + 4*g) = pw;
      if(dtile && gs < 1056)
        *(ushort4*)(phikg + (size_t)gs*128 + mt*16 + 4*g) = pw;
    }
    #pragma unroll
    for(int i=0;i<4;i++){
      int flat = tid + 256*i;
      int sv = flat >> 4, d4 = (flat & 15)*4;
      float x[4] = {vreg[i].x, vreg[i].y, vreg[i].z, vreg[i].w};
      #pragma unroll
      for(int j=0;j<4;j++){
        int d = d4 + j;
        vt[d*72 + (sv ^ (8*((d>>2)&7)))] = f2b(x[j]);
      }
    }
    __syncthreads();
    #pragma unroll
    for(int ks=0;ks<2;ks++){
      short8 af0 = *(const short8*)(phit + ((2*wave+0)*16 + r16)*72 + ks*32 + g*8);
      short8 af1 = *(const short8*)(phit + ((2*wave+1)*16 + r16)*72 + ks*32 + g*8);
      short8 bf[4];
      #pragma unroll
      for(int dt=0;dt<4;dt++){
        int d = dt*16 + r16;
        int col = (ks*32 + g*8) ^ (8*((d>>2)&7));
        bf[dt] = *(const short8*)(vt + d*72 + col);
      }
      #pragma unroll
      for(int dt=0;dt<4;dt++){
        kvacc[0][dt] = __builtin_amdgcn_mfma_f32_16x16x32_bf16(af0, bf[dt], kvacc[0][dt], 0, 0, 0);
        kvacc[1][dt] = __builtin_amdgcn_mfma_f32_16x16x32_bf16(af1, bf[dt], kvacc[1][dt], 0, 0, 0);
      }
      #pragma unroll
      for(int j=0;j<8;j++){ k1p0 += b2f((u16)af0[j]); k1p1 += b2f((u16)af1[j]); }
    }
    __syncthreads();
  }
  k1p0 += __shfl_xor(k1p0, 16); k1p0 += __shfl_xor(k1p0, 32);
  k1p1 += __shfl_xor(k1p1, 16); k1p1 += __shfl_xor(k1p1, 32);
  if(l < 16){
    atomicAdd(ws + WS_K1 + combo*128 + (2*wave+0)*16 + l, k1p0);
    atomicAdd(ws + WS_K1 + combo*128 + (2*wave+1)*16 + l, k1p1);
  }
  #pragma unroll
  for(int mi=0;mi<2;mi++){
    #pragma unroll
    for(int dt=0;dt<4;dt++){
      #pragma unroll
      for(int rr=0;rr<4;rr++){
        int m = (2*wave+mi)*16 + 4*g + rr;
        int d = dt*16 + r16;
        atomicAdd(ws + WS_KV + (size_t)combo*8192 + m*64 + d, kvacc[mi][dt][rr]);
      }
    }
  }
}

// ================= k_qm: fused k_q + k_main =================
// r11: T14 hoist + write-swizzles. r13b: cj stride 104, LDS peak 53760 B -> 3 blocks
// fit by LDS (161280 <= 163840). r15: launch_bounds back to (256,2) — the (256,3)
// bound forced VGPR 120->84 + scratch spills (r14: WRITE_SIZE 3x). Natural alloc
// (~120 regs < 170 = 512/3) lets the HW schedule the 3rd block WITHOUT spills.
__global__ __launch_bounds__(256, 2) void k_qm(const float* __restrict__ qry,
                                               const float* __restrict__ key,
                                               const float* __restrict__ val,
                                               const float* __restrict__ proj,
                                               float* __restrict__ ws,
                                               float* __restrict__ out){
  __shared__ __align__(16) u16 buf[26880];   // 53760 B
  // phase A layout
  u16* kvtA   = buf;            // [d][m] stride 136, col-swizzled
  u16* phiqsA = buf + 8704;     // [q][m] stride 136
  float* k1s  = (float*)(buf + 17408);   // 128 floats
  // phase B layout (overlays; all phase-A reads complete before reuse)
  u16* khs  = buf;              // [96][72]
  u16* kls  = buf + 6912;
  u16* phik = buf + 13824;      // [96][136] -> ends 26880
  u16* cjh  = buf;              // [64][104], col-swizzled (&3)
  u16* cjl  = buf + 6656;
  u16* vt   = buf + 13312;      // [64][104], col-swizzled (&3)
  u16* vtl  = buf + 19968;      // ends 26624

  const int tid = threadIdx.x;
  const int wave = tid >> 6, l = tid & 63;
  const int g = l >> 4, r16 = l & 15;
  const int qt = blockIdx.x, combo = blockIdx.y;
  const int c = combo >> 5, b = (combo >> 3) & 3, h = combo & 7;
  const int s_base = qt*64 - 16;
  const float* projc = proj + c*8192;
  const float stab = ws[WS_PMAX + combo];
  const f32x4 zero4 = {0.f,0.f,0.f,0.f};

  // ---- prefetch ALL phase-B global inputs (consumed after A2) — T14
  const u16* phikg = ((const u16*)(ws + WS_PHIK)) + (size_t)combo*1056*128;
  float4 kreg[6], vreg[6];
  ushort4 preg[12];
  #pragma unroll
  for(int i=0;i<6;i++){
    int flat = tid + 256*i;
    int j = flat >> 4, e4 = (flat & 15)*4;
    int s = s_base + j;
    float4 u = {0.f,0.f,0.f,0.f};
    float4 w4 = {0.f,0.f,0.f,0.f};
    if(s >= 0){
      u  = *(const float4*)(key + (((size_t)b*4096 + s)*8 + h)*64 + e4);
      w4 = *(const float4*)(val + (((size_t)b*4096 + s)*8 + h)*64 + e4);
    }
    kreg[i] = u; vreg[i] = w4;
  }
  #pragma unroll
  for(int i=0;i<12;i++){
    int flat = tid + 256*i;
    int j = flat >> 5, c4 = (flat & 31)*4;
    int s = s_base + j;
    ushort4 p = {0,0,0,0};
    if(s >= 0) p = *(const ushort4*)(phikg + (size_t)s*128 + c4);
    preg[i] = p;
  }

  // ---- A0: k1s + kv -> LDS (transposed bf16, col-swizzled)
  if(tid < 128) k1s[tid] = ws[WS_K1 + combo*128 + tid];
  const float* kvg = ws + WS_KV + (size_t)combo*8192;
  #pragma unroll
  for(int i=0;i<8;i++){
    int flat = tid + 256*i;
    int m = flat >> 4, d4 = (flat & 15)*4;
    int col = m ^ (8*((flat & 15) & 7));   // swz by (d>>2)&7 = (flat&15)&7
    float4 u = *(const float4*)(kvg + m*64 + d4);
    kvtA[(d4+0)*136 + col] = f2b(u.x);
    kvtA[(d4+1)*136 + col] = f2b(u.y);
    kvtA[(d4+2)*136 + col] = f2b(u.z);
    kvtA[(d4+3)*136 + col] = f2b(u.w);
  }
  // q fragments (hi/lo) — used by BOTH logq (phase A) and scores (phase B)
  const int qrow = qt*64 + wave*16 + r16;
  const float* qr = qry + (size_t)(b*4096 + (c*1024 + qrow))*512 + h*64;
  float areg[16];
  #pragma unroll
  for(int ks=0;ks<2;ks++){
    float4 u0 = *(const float4*)(qr + ks*32 + g*8);
    float4 u1 = *(const float4*)(qr + ks*32 + g*8 + 4);
    areg[ks*8+0]=u0.x; areg[ks*8+1]=u0.y; areg[ks*8+2]=u0.z; areg[ks*8+3]=u0.w;
    areg[ks*8+4]=u1.x; areg[ks*8+5]=u1.y; areg[ks*8+6]=u1.z; areg[ks*8+7]=u1.w;
  }
  float qsq = 0.f;
  #pragma unroll
  for(int e=0;e<16;e++) qsq = fmaf(areg[e], areg[e], qsq);
  qsq += __shfl_xor(qsq, 16);
  qsq += __shfl_xor(qsq, 32);
  qsq *= 0.5f;
  short8 ah[2], al[2];
  #pragma unroll
  for(int ks=0;ks<2;ks++){
    #pragma unroll
    for(int j=0;j<8;j++){
      float x = areg[ks*8+j];
      u16 hb = f2b(x);
      ah[ks][j] = (short)hb;
      al[ks][j] = (short)f2b(x - b2f(hb));
    }
  }
  __syncthreads();   // kvtA, k1s ready

  // ---- A1: logq MFMA
  f32x4 acc[8];
  #pragma unroll
  for(int mt=0;mt<8;mt++) acc[mt] = zero4;
  #pragma unroll
  for(int ks=0;ks<2;ks++){
    #pragma unroll
    for(int mt=0;mt<8;mt++){
      const float* pb = projc + (mt*16 + r16)*64 + ks*32 + g*8;
      float4 u0 = *(const float4*)pb;
      float4 u1 = *(const float4*)(pb + 4);
      float x[8] = {u0.x,u0.y,u0.z,u0.w,u1.x,u1.y,u1.z,u1.w};
      short8 pph, ppl;
      #pragma unroll
      for(int j=0;j<8;j++){
        u16 hb = f2b(x[j]);
        pph[j] = (short)hb;
        ppl[j] = (short)f2b(x[j] - b2f(hb));
      }
      acc[mt] = __builtin_amdgcn_mfma_f32_16x16x32_bf16(ah[ks], pph, acc[mt], 0, 0, 0);
      acc[mt] = __builtin_amdgcn_mfma_f32_16x16x32_bf16(ah[ks], ppl, acc[mt], 0, 0, 0);
      acc[mt] = __builtin_amdgcn_mfma_f32_16x16x32_bf16(al[ks], pph, acc[mt], 0, 0, 0);
    }
  }
  float qsr[4];
  #pragma unroll
  for(int r=0;r<4;r++) qsr[r] = __shfl(qsq, 4*g + r);
  float amax[4];
  #pragma unroll
  for(int r=0;r<4;r++){
    float m = -3e38f;
    #pragma unroll
    for(int mt=0;mt<8;mt++) m = fmaxf(m, acc[mt][r]);
    m = fmaxf(m, __shfl_xor(m, 1));
    m = fmaxf(m, __shfl_xor(m, 2));
    m = fmaxf(m, __shfl_xor(m, 4));
    m = fmaxf(m, __shfl_xor(m, 8));
    amax[r] = m;
  }
  float lrp[4] = {0.f,0.f,0.f,0.f};
  #pragma unroll
  for(int mt=0;mt<8;mt++){
    const float k1v = k1s[mt*16 + r16];
    #pragma unroll
    for(int r=0;r<4;r++){
      float phv = __expf(acc[mt][r] - amax[r]);
      phiqsA[(wave*16 + 4*g + r)*136 + mt*16 + r16] = f2b(phv);
      lrp[r] = fmaf(phv, k1v, lrp[r]);
    }
  }
  #pragma unroll
  for(int r=0;r<4;r++){
    lrp[r] += __shfl_xor(lrp[r], 1);
    lrp[r] += __shfl_xor(lrp[r], 2);
    lrp[r] += __shfl_xor(lrp[r], 4);
    lrp[r] += __shfl_xor(lrp[r], 8);
  }
  float plsr[4], lr1r[4];
  #pragma unroll
  for(int r=0;r<4;r++){
    plsr[r] = amax[r] - qsr[r] + stab - LOGM;
    lr1r[r] = lrp[r];
  }
  __syncthreads();   // phiqsA complete

  // ---- A2: phi_q A-fragments + lr_v MFMA (f32, kept in regs)
  short8 pa[4];
  #pragma unroll
  for(int ks=0;ks<4;ks++)
    pa[ks] = *(const short8*)(phiqsA + (wave*16 + r16)*136 + ks*32 + g*8);
  f32x4 lacc[4];
  #pragma unroll
  for(int dt=0;dt<4;dt++) lacc[dt] = zero4;
  #pragma unroll
  for(int ks=0;ks<4;ks++){
    #pragma unroll
    for(int dt=0;dt<4;dt++){
      int drow = dt*16 + r16;
      int colb = (ks*32 + g*8) ^ (8*((drow>>2)&7));
      short8 bfr = *(const short8*)(kvtA + drow*136 + colb);
      lacc[dt] = __builtin_amdgcn_mfma_f32_16x16x32_bf16(pa[ks], bfr, lacc[dt], 0, 0, 0);
    }
  }
  __syncthreads();   // all phase-A LDS reads done; buf may be overwritten

  // ---- B0: write prefetched k window (hi/lo) + phi_k window to LDS
  #pragma unroll
  for(int i=0;i<6;i++){
    int flat = tid + 256*i;
    int j = flat >> 4, e4 = (flat & 15)*4;
    float4 u = kreg[i];
    ushort4 hh, ll;
    hh.x = f2b(u.x); ll.x = f2b(u.x - b2f(hh.x));
    hh.y = f2b(u.y); ll.y = f2b(u.y - b2f(hh.y));
    hh.z = f2b(u.z); ll.z = f2b(u.z - b2f(hh.z));
    hh.w = f2b(u.w); ll.w = f2b(u.w - b2f(hh.w));
    *(ushort4*)(khs + j*72 + e4) = hh;
    *(ushort4*)(kls + j*72 + e4) = ll;
  }
  #pragma unroll
  for(int i=0;i<12;i++){
    int flat = tid + 256*i;
    int j = flat >> 5, c4 = (flat & 31)*4;
    *(ushort4*)(phik + j*136 + c4) = preg[i];
  }
  __syncthreads();

  // ---- B1: S (scores) and D (dots_p) over the full 16x96 stripe
  f32x4 sacc[6], dacc[6];
  #pragma unroll
  for(int j=0;j<6;j++){ sacc[j] = zero4; dacc[j] = zero4; }
  #pragma unroll
  for(int j=0;j<6;j++){
    #pragma unroll
    for(int ks=0;ks<2;ks++){
      short8 kbh = *(const short8*)(khs + (j*16 + r16)*72 + ks*32 + g*8);
      short8 kbl = *(const short8*)(kls + (j*16 + r16)*72 + ks*32 + g*8);
      sacc[j] = __builtin_amdgcn_mfma_f32_16x16x32_bf16(ah[ks], kbh, sacc[j], 0, 0, 0);
      sacc[j] = __builtin_amdgcn_mfma_f32_16x16x32_bf16(al[ks], kbh, sacc[j], 0, 0, 0);
      sacc[j] = __builtin_amdgcn_mfma_f32_16x16x32_bf16(ah[ks], kbl, sacc[j], 0, 0, 0);
    }
    #pragma unroll
    for(int ks=0;ks<4;ks++){
      short8 pb = *(const short8*)(phik + (j*16 + r16)*136 + ks*32 + g*8);
      dacc[j] = __builtin_amdgcn_mfma_f32_16x16x32_bf16(pa[ks], pb, dacc[j], 0, 0, 0);
    }
  }
  __syncthreads();   // all B1 LDS reads done; region reused below

  // ---- B2: v -> LDS (transposed, hi/lo, col-swizzled); softmax; cj -> LDS (swizzled)
  #pragma unroll
  for(int i=0;i<6;i++){
    int flat = tid + 256*i;
    int j = flat >> 4, e4 = (flat & 15)*4;
    int e = flat & 15;
    int col = j ^ (8*(e & 3));             // swz by (row>>2)&3 = e&3
    float4 u = vreg[i];
    u16 h0 = f2b(u.x), h1 = f2b(u.y), h2 = f2b(u.z), h3 = f2b(u.w);
    vt[(e4+0)*104 + col] = h0; vtl[(e4+0)*104 + col] = f2b(u.x - b2f(h0));
    vt[(e4+1)*104 + col] = h1; vtl[(e4+1)*104 + col] = f2b(u.y - b2f(h1));
    vt[(e4+2)*104 + col] = h2; vtl[(e4+2)*104 + col] = f2b(u.z - b2f(h2));
    vt[(e4+3)*104 + col] = h3; vtl[(e4+3)*104 + col] = f2b(u.w - b2f(h3));
  }
  const int rowb = wave*16 + 4*g;
  float m1r[4] = {-1e30f,-1e30f,-1e30f,-1e30f};
  #pragma unroll
  for(int j=0;j<6;j++){
    #pragma unroll
    for(int r=0;r<4;r++){
      int rel = 16*j + r16 - 16 - (rowb + r);
      bool ok = (rel >= -16) && (rel < 16) && (s_base + 16*j + r16 >= 0);
      if(ok) m1r[r] = fmaxf(m1r[r], sacc[j][r]);
    }
  }
  #pragma unroll
  for(int r=0;r<4;r++){
    m1r[r] = fmaxf(m1r[r], __shfl_xor(m1r[r], 1));
    m1r[r] = fmaxf(m1r[r], __shfl_xor(m1r[r], 2));
    m1r[r] = fmaxf(m1r[r], __shfl_xor(m1r[r], 4));
    m1r[r] = fmaxf(m1r[r], __shfl_xor(m1r[r], 8));
  }
  float ser[4] = {0.f,0.f,0.f,0.f}, wpr[4] = {0.f,0.f,0.f,0.f};
  #pragma unroll
  for(int j=0;j<6;j++){
    #pragma unroll
    for(int r=0;r<4;r++){
      int rel = 16*j + r16 - 16 - (rowb + r);
      bool ok = (rel >= -16) && (rel < 16) && (s_base + 16*j + r16 >= 0);
      if(ok){
        ser[r] += __expf(sacc[j][r] - m1r[r]);
        wpr[r] += dacc[j][r];
      }
    }
  }
  #pragma unroll
  for(int r=0;r<4;r++){
    ser[r] += __shfl_xor(ser[r], 1); ser[r] += __shfl_xor(ser[r], 2);
    ser[r] += __shfl_xor(ser[r], 4); ser[r] += __shfl_xor(ser[r], 8);
    wpr[r] += __shfl_xor(wpr[r], 1); wpr[r] += __shfl_xor(wpr[r], 2);
    wpr[r] += __shfl_xor(wpr[r], 4); wpr[r] += __shfl_xor(wpr[r], 8);
  }
  float lnr[4], scr[4];
  #pragma unroll
  for(int r=0;r<4;r++){
    float qk_lse = m1r[r] + __logf(ser[r]);
    float lrem = fmaxf(lr1r[r] - wpr[r], 1e-37f);
    float bb = __logf(lrem) + plsr[r];
    float ln = fmaxf(qk_lse, bb) + log1pf(__expf(-fabsf(qk_lse - bb)));
    lnr[r] = ln;
    scr[r] = __expf(plsr[r] - ln);
  }
  #pragma unroll
  for(int j=0;j<6;j++){
    #pragma unroll
    for(int r=0;r<4;r++){
      int rel = 16*j + r16 - 16 - (rowb + r);
      bool ok = (rel >= -16) && (rel < 16) && (s_base + 16*j + r16 >= 0);
      float cj = ok ? (__expf(sacc[j][r] - lnr[r]) - scr[r]*dacc[j][r]) : 0.f;
      u16 hb = f2b(cj);
      int row = rowb + r;
      int col = (16*j + r16) ^ (8*((row>>2)&3));   // mask bits 3-4 only: col <= 95 < 104
      cjh[row*104 + col] = hb;
      cjl[row*104 + col] = f2b(cj - b2f(hb));
    }
  }
  __syncthreads();

  // ---- B3: out = cj . v_win (hi/lo split) + scale*lr_v (lacc, f32)
  f32x4 oacc[4];
  #pragma unroll
  for(int dt=0;dt<4;dt++) oacc[dt] = zero4;
  const int qrowB = wave*16 + r16;
  const int cw = (qrowB >> 2) & 3;        // matches write mask (&3)
  #pragma unroll
  for(int ks=0;ks<3;ks++){
    int ccol = (ks*32 + g*8) ^ (8*cw);    // base^mask <= 88, +8 = 96 <= 104
    short8 ch = *(const short8*)(cjh + qrowB*104 + ccol);
    short8 cl = *(const short8*)(cjl + qrowB*104 + ccol);
    #pragma unroll
    for(int dt=0;dt<4;dt++){
      int vrow = dt*16 + r16;
      int vcol = (ks*32 + g*8) ^ (8*((vrow>>2)&3));
      short8 vbh = *(const short8*)(vt  + vrow*104 + vcol);
      short8 vbl = *(const short8*)(vtl + vrow*104 + vcol);
      oacc[dt] = __builtin_amdgcn_mfma_f32_16x16x32_bf16(ch, vbh, oacc[dt], 0, 0, 0);
      oacc[dt] = __builtin_amdgcn_mfma_f32_16x16x32_bf16(cl, vbh, oacc[dt], 0, 0, 0);
      oacc[dt] = __builtin_amdgcn_mfma_f32_16x16x32_bf16(ch, vbl, oacc[dt], 0, 0, 0);
    }
  }
  #pragma unroll
  for(int r=0;r<4;r++){
    int row = rowb + r;                      // query within 64
    float* ob = out + ((((size_t)b*8 + h)*4096) + (size_t)c*1024 + qt*64 + row)*64;
    #pragma unroll
    for(int dt=0;dt<4;dt++)
      ob[dt*16 + r16] = oacc[dt][r] + scr[r]*lacc[dt][r];
  }
}

extern "C" void kernel_launch(void* const* d_in, const int* in_sizes, int n_in,
                              void* d_out, int out_size, void* d_ws, size_t ws_size,
                              hipStream_t stream){
  (void)in_sizes; (void)n_in; (void)out_size; (void)ws_size;
  const float* q = (const float*)d_in[0];
  const float* k = (const float*)d_in[1];
  const float* v = (const float*)d_in[2];
  const float* p = (const float*)d_in[3];
  float* out = (float*)d_out;
  float* ws = (float*)d_ws;
  k_zs  <<<dim3(1040),   256, 0, stream>>>(p, ws);
  k_phi <<<dim3(4,128),  256, 0, stream>>>(k, v, p, ws);
  k_qm  <<<dim3(16,128), 256, 0, stream>>>(q, k, v, p, ws, out);
}